// Round 7
// baseline (26.453 us; speedup 1.0000x reference)
//
#include <hip/hip_runtime.h>

// SurfEval: NURBS surface evaluation (B=4, 1024x1024 grid, 4x4 basis window).
// R6: amortized-window stage 2 — 4 consecutive v per lane share one 5-entry
// tu window (span run length = 1023/126 ~ 8.1 > 4, so <=2 adjacent spans per
// quad). LDS reads: 5 ds_read_b128 per 4 points (vs 4 per point in R0-R5).
// Per-point weights selected from the shifted 5-vector via cndmask (o in
// {0,1}). Stores: 3x dwordx4 per lane (48B contiguous). Wave-private tu as
// in R5 (no barriers). rcp divide (absmax 7.8e-3 << 5.9e-2 threshold).

#define OUT_U 1024
#define OUT_V 1024
#define MCTRL 128
#define NCTRL 128

typedef float f4 __attribute__((ext_vector_type(4)));

__global__ __launch_bounds__(256) void surf_eval_kernel(
    const f4*  __restrict__ ctrl,   // (B,M,N) as float4
    const f4*  __restrict__ Nu,     // (OUT_U)
    const f4*  __restrict__ Nv,     // (OUT_V)
    const int* __restrict__ uspan,  // (OUT_U)
    const int* __restrict__ vspan,  // (OUT_V)
    float*     __restrict__ out)    // (B,OUT_U,OUT_V,3)
{
    __shared__ f4 tu[4][NCTRL];     // per-wave private buffers, 8KB

    const int tid  = threadIdx.x;
    const int w    = tid >> 6;      // wave id == batch index
    const int lane = tid & 63;
    const int u    = blockIdx.x >> 1;
    const int half = blockIdx.x & 1;

    const int us = uspan[u];        // block-uniform
    const f4  nu = Nu[u];

    // Stage 1 (per wave, its own batch): tu[j] = sum_l nu[l]*ctrl[w,us-3+l,j]
    const f4* win = ctrl + ((size_t)(w * MCTRL + (us - 3)) * NCTRL);
#pragma unroll
    for (int h = 0; h < 2; ++h) {
        const int j = lane + h * 64;
        f4 acc = nu.x * win[j];
        acc += nu.y * win[NCTRL + j];
        acc += nu.z * win[2 * NCTRL + j];
        acc += nu.w * win[3 * NCTRL + j];
        tu[w][j] = acc;
    }
    // No barrier: wave-private LDS region; same-wave ds ordering via lgkmcnt.

    // Stage 2: 2 iterations x 4 consecutive v per lane.
    const size_t outrow = ((size_t)w * OUT_U + (size_t)u) * OUT_V;
#pragma unroll
    for (int k = 0; k < 2; ++k) {
        const int v0 = (half << 9) + (k << 8) + (lane << 2);
        const int4 vs4 = *(const int4*)(vspan + v0);  // nondecreasing, max-min<=1
        const int m  = vs4.x;
        const int wb = m - 3;                         // window base, >=0

        // Shared 5-entry window (5th clamped; its weight is 0 when unused).
        f4 W0 = tu[w][wb];
        f4 W1 = tu[w][wb + 1];
        f4 W2 = tu[w][wb + 2];
        f4 W3 = tu[w][wb + 3];
        f4 W4 = tu[w][min(wb + 4, NCTRL - 1)];

        float r[12];
#pragma unroll
        for (int p = 0; p < 4; ++p) {
            const int vsp = (p == 0) ? vs4.x : (p == 1) ? vs4.y
                          : (p == 2) ? vs4.z : vs4.w;
            const bool c = (vsp != m);               // o_p in {0,1}
            const f4 nv = Nv[v0 + p];

            // Shifted weights: c ? [0,n0,n1,n2,n3] : [n0,n1,n2,n3,0]
            const float w0 = c ? 0.0f : nv.x;
            const float w1 = c ? nv.x : nv.y;
            const float w2 = c ? nv.y : nv.z;
            const float w3 = c ? nv.z : nv.w;
            const float w4 = c ? nv.w : 0.0f;

            f4 acc = w0 * W0;
            acc += w1 * W1;
            acc += w2 * W2;
            acc += w3 * W3;
            acc += w4 * W4;

            const float inv = __builtin_amdgcn_rcpf(acc.w);
            r[p * 3 + 0] = acc.x * inv;
            r[p * 3 + 1] = acc.y * inv;
            r[p * 3 + 2] = acc.z * inv;
        }

        f4* op = (f4*)(out + (outrow + (size_t)v0) * 3);
        f4 s0 = {r[0], r[1], r[2],  r[3]};
        f4 s1 = {r[4], r[5], r[6],  r[7]};
        f4 s2 = {r[8], r[9], r[10], r[11]};
        __builtin_nontemporal_store(s0, op);
        __builtin_nontemporal_store(s1, op + 1);
        __builtin_nontemporal_store(s2, op + 2);
    }
}

extern "C" void kernel_launch(void* const* d_in, const int* in_sizes, int n_in,
                              void* d_out, int out_size, void* d_ws, size_t ws_size,
                              hipStream_t stream) {
    const f4*  ctrl  = (const f4*)d_in[0];
    const f4*  Nu    = (const f4*)d_in[1];
    const f4*  Nv    = (const f4*)d_in[2];
    const int* uspan = (const int*)d_in[3];
    const int* vspan = (const int*)d_in[4];
    float*     out   = (float*)d_out;

    const int nblocks = OUT_U * 2;  // (u, half): 2048 blocks
    surf_eval_kernel<<<nblocks, 256, 0, stream>>>(ctrl, Nu, Nv, uspan, vspan, out);
}